// Round 4
// baseline (238.970 us; speedup 1.0000x reference)
//
#include <hip/hip_runtime.h>

// Problem constants
#define IN_DIM   256
#define CODE_LEN 128
#define MEM_LEN  65536
#define BETA     1.0f

// Output layout (floats): [0]=loss, [1..]=memory (MEM_LEN*CODE_LEN),
// then mem_data (MEM_LEN*IN_DIM), then mem_idx (MEM_LEN, as float)
#define OUT_MEM_OFF   1
#define OUT_MD_OFF    (1 + MEM_LEN*CODE_LEN)            // 8388609
#define OUT_IDX_OFF   (OUT_MD_OFF + MEM_LEN*IN_DIM)     // 25165825

// Workspace (float indices) — tiny now:
#define WS_ENC   0      // float[128]
#define WS_LOSS  128    // 8 x uint replicated min (init 0xFFFFFFFF)
#define WS_KEY   136    // u64 at byte 544 (8B aligned, init all-ones)

// Column-accumulator scratch lives INSIDE the out 'memory' region (it is
// fully overwritten later by k_dist's memory copy — safe by dispatch order,
// and avoids assuming a large d_ws). 16 replicas x (256 sum + 256 sumsq).
#define SB_OFF    OUT_MEM_OFF    // out[1 .. 1+8192)
#define N_REP     16

#define MD_TILES  (MEM_LEN*IN_DIM/4)    // 4194304 = 4096*256*4  EXACT
#define MEM_TILES (MEM_LEN*CODE_LEN/4)  // 2097152 = 2048*256*4  EXACT

typedef float vfloat4 __attribute__((ext_vector_type(4)));

// Unaligned (4B-phase) 16-byte store; instruction-level alignment was proven
// irrelevant (R0 vs R3: identical 60us with either side misaligned).
__device__ __forceinline__ void store16u(float* dst, vfloat4 v) {
    __builtin_memcpy(dst, &v, 16);
}

// ---------------------------------------------------------------------------
// init: zero scratch replicas (in out), set loss/key sentinels.
__global__ void k_init(float* __restrict__ out, float* __restrict__ ws) {
    const int t = threadIdx.x;            // 256 threads
    #pragma unroll
    for (int j = 0; j < 2 * N_REP; ++j) out[SB_OFF + t + j * 256] = 0.f;
    if (t < 8) ((unsigned int*)ws)[WS_LOSS + t] = 0xFFFFFFFFu;
    if (t == 0) *((unsigned long long*)(ws + WS_KEY)) = ~0ull;
}

// ---------------------------------------------------------------------------
// A: blocks [0,4096): copy mem_data -> out + per-column sum/sumsq.
//    Contiguous grid-stride shape (fill/copy-proven): gtid = bid*256+t,
//    tiles gtid + i*1048576, i<4 — per-wave contiguous 1KB, exact coverage,
//    4 tiles/thread => fast block turnover; 16 blocks/CU queued (~8 resident
//    via launch_bounds(256,8)) so tail phases (LDS reduce + atomics) overlap
//    other blocks' streaming instead of idling HBM in lockstep.
//    Column accumulators: 16 replicas (block bid -> replica bid&15) cut the
//    per-address atomic chain 1024 -> 256.
//    blocks [4096,4160): mem_idx copy + packed argmin.
__global__ __launch_bounds__(256, 8) void k_stats(
        const float* __restrict__ mem_data,
        const int*   __restrict__ mem_idx,
        float* __restrict__ out,
        float* __restrict__ ws) {
    const int t = threadIdx.x;
    const int bid = blockIdx.x;

    if (bid >= 4096) {
        __shared__ unsigned long long red[256];
        const int tid = (bid - 4096) * 256 + t;             // 0..16383
        unsigned long long local = ~0ull;
        #pragma unroll
        for (int rep = 0; rep < 4; ++rep) {
            int i = tid + rep * 16384;
            int v = mem_idx[i];
            out[OUT_IDX_OFF + i] = (float)v;
            unsigned long long key =
                (((unsigned long long)(unsigned int)(v ^ (int)0x80000000)) << 32)
                | (unsigned int)i;
            local = local < key ? local : key;
        }
        red[t] = local;
        __syncthreads();
        for (int s = 128; s > 0; s >>= 1) {
            if (t < s) { unsigned long long o = red[t + s]; if (o < red[t]) red[t] = o; }
            __syncthreads();
        }
        if (t == 0) atomicMin((unsigned long long*)(ws + WS_KEY), red[0]);
        return;
    }

    __shared__ float lsum[256], lsq[256];
    lsum[t] = 0.f; lsq[t] = 0.f;
    __syncthreads();

    float* __restrict__ out_md = out + OUT_MD_OFF;
    const int gtid = bid * 256 + t;                         // 0..1048575
    float s0=0,s1=0,s2=0,s3=0,q0=0,q1=0,q2=0,q3=0;

    vfloat4 v[4];
    #pragma unroll
    for (int i = 0; i < 4; ++i)
        v[i] = ((const vfloat4*)mem_data)[gtid + i * 1048576];   // aligned dwordx4
    #pragma unroll
    for (int i = 0; i < 4; ++i) {
        store16u(out_md + 4 * (gtid + i * 1048576), v[i]);       // plain, unaligned
        s0 += v[i].x; q0 += v[i].x * v[i].x;
        s1 += v[i].y; q1 += v[i].y * v[i].y;
        s2 += v[i].z; q2 += v[i].z * v[i].z;
        s3 += v[i].w; q3 += v[i].w * v[i].w;
    }

    // columns fixed per thread: 4*1048576 % 256 == 0 and 4*256*bid % 256 == 0
    const int c0 = (4 * t) & 255;                           // c0 <= 252, no wrap
    atomicAdd(&lsum[c0    ], s0);  atomicAdd(&lsq[c0    ], q0);
    atomicAdd(&lsum[c0 + 1], s1);  atomicAdd(&lsq[c0 + 1], q1);
    atomicAdd(&lsum[c0 + 2], s2);  atomicAdd(&lsq[c0 + 2], q2);
    atomicAdd(&lsum[c0 + 3], s3);  atomicAdd(&lsq[c0 + 3], q3);
    __syncthreads();
    float* __restrict__ sb = out + SB_OFF + (bid & (N_REP - 1)) * 512;
    atomicAdd(&sb[t      ], lsum[t]);
    atomicAdd(&sb[t + 256], lsq[t]);
}

// ---------------------------------------------------------------------------
// B: mean/std -> normalize x -> enc = new @ W^T + b.  1 block x 256 threads.
//    Reads the replica accumulators from out-scratch (kernel boundary =>
//    coherent); folds replicas in fixed ascending order.
__global__ void k_enc(const float* __restrict__ x,
                      const float* __restrict__ W,
                      const float* __restrict__ b,
                      const float* __restrict__ out,
                      float* __restrict__ ws) {
    __shared__ float nrm[IN_DIM];
    const int t = threadIdx.x;
    float sum = 0.f, sq = 0.f;
    #pragma unroll
    for (int r = 0; r < N_REP; ++r) {
        sum += out[SB_OFF + r * 512 + t];
        sq  += out[SB_OFF + r * 512 + 256 + t];
    }
    float mean = sum * (1.0f / MEM_LEN);
    float var  = (sq - sum * sum * (1.0f / MEM_LEN)) * (1.0f / (MEM_LEN - 1));
    var = fmaxf(var, 0.0f);
    float sd = sqrtf(var);
    nrm[t] = (sd == 0.0f) ? 0.0f : (x[t] - mean) / sd;
    __syncthreads();
    if (t < CODE_LEN) {
        float acc = b[t];
        const float* w = W + t * IN_DIM;
        #pragma unroll 8
        for (int d = 0; d < IN_DIM; ++d) acc += nrm[d] * w[d];
        ws[WS_ENC + t] = acc;
    }
}

// ---------------------------------------------------------------------------
// C: memory copy + L1 distance per row + global min. Same streaming shape:
//    2048 blocks, 4 rows/32-lane-group via i-stride 524288 tiles. One aligned
//    load serves both the distance math and the (unaligned, plain) store.
//    This copy also overwrites the out-scratch region (after k_enc read it).
//    Loss min replicated 8-way (chain 2048 -> 256).
__global__ __launch_bounds__(256, 8) void k_dist(
        const float* __restrict__ memory,
        float* __restrict__ out,
        float* __restrict__ ws) {
    __shared__ vfloat4 es[32];
    __shared__ float red[256];
    const int t = threadIdx.x;
    if (t < 32) es[t] = ((const vfloat4*)(ws + WS_ENC))[t];
    __syncthreads();
    const int lane = t & 31;
    const vfloat4 e = es[lane];
    float* __restrict__ out_mem = out + OUT_MEM_OFF;
    const int gtid = blockIdx.x * 256 + t;                  // 0..524287
    float localmin = 3.4e38f;

    vfloat4 m[4];
    #pragma unroll
    for (int i = 0; i < 4; ++i)
        m[i] = ((const vfloat4*)memory)[gtid + i * 524288];       // aligned
    #pragma unroll
    for (int i = 0; i < 4; ++i) {
        store16u(out_mem + 4 * (gtid + i * 524288), m[i]);        // plain, unaligned
        float d = fabsf(m[i].x - e.x) + fabsf(m[i].y - e.y)
                + fabsf(m[i].z - e.z) + fabsf(m[i].w - e.w);
        #pragma unroll
        for (int off = 16; off > 0; off >>= 1) d += __shfl_xor(d, off, 32);
        localmin = fminf(localmin, d);
    }

    red[t] = localmin;
    __syncthreads();
    for (int s2 = 128; s2 > 0; s2 >>= 1) {
        if (t < s2) red[t] = fminf(red[t], red[t + s2]);
        __syncthreads();
    }
    if (t == 0)
        atomicMin((unsigned int*)(ws + WS_LOSS + (blockIdx.x & 7)),
                  __float_as_uint(red[0]));
}

// ---------------------------------------------------------------------------
// E: fold 8 loss replicas, write loss; conditional scatter. 1 block x 256.
__global__ void k_final(const float* __restrict__ x,
                        const int* __restrict__ count,
                        const float* __restrict__ ws,
                        float* __restrict__ d_out) {
    const int t = threadIdx.x;
    unsigned int lb = ((const unsigned int*)ws)[WS_LOSS];
    #pragma unroll
    for (int r = 1; r < 8; ++r) {
        unsigned int o = ((const unsigned int*)ws)[WS_LOSS + r];
        lb = o < lb ? o : lb;
    }
    const float loss = __uint_as_float(lb);
    if (t == 0) d_out[0] = loss;
    if (loss <= BETA) {
        unsigned long long key = *(const unsigned long long*)(ws + WS_KEY);
        unsigned int pos = (unsigned int)(key & 0xFFFFFFFFull);
        if (t < CODE_LEN)
            d_out[OUT_MEM_OFF + (size_t)pos * CODE_LEN + t] = ws[WS_ENC + t];
        d_out[OUT_MD_OFF + (size_t)pos * IN_DIM + t] = x[t];
        if (t == 0)
            d_out[OUT_IDX_OFF + pos] = (float)count[0];
    }
}

// ---------------------------------------------------------------------------
extern "C" void kernel_launch(void* const* d_in, const int* in_sizes, int n_in,
                              void* d_out, int out_size, void* d_ws, size_t ws_size,
                              hipStream_t stream) {
    const float* x        = (const float*)d_in[0];
    const float* memory   = (const float*)d_in[1];
    const float* mem_data = (const float*)d_in[2];
    const int*   mem_idx  = (const int*)d_in[3];
    const float* W        = (const float*)d_in[4];
    const float* b        = (const float*)d_in[5];
    const int*   count    = (const int*)d_in[6];
    float* out = (float*)d_out;
    float* ws  = (float*)d_ws;

    k_init<<<1, 256, 0, stream>>>(out, ws);
    k_stats<<<4160, 256, 0, stream>>>(mem_data, mem_idx, out, ws);
    k_enc<<<1, 256, 0, stream>>>(x, W, b, out, ws);
    k_dist<<<2048, 256, 0, stream>>>(memory, out, ws);
    k_final<<<1, 256, 0, stream>>>(x, count, ws, out);
}